// Round 2
// baseline (741.112 us; speedup 1.0000x reference)
//
#include <hip/hip_runtime.h>

// ParabolicPool2D: out[b,c,i,j] = max_{u,v} f[b,c, 2i+u-3, 2j+v-3] + hu[u] + hu[v]
// Separable under max-plus: h[u,v] = hu[u] + hu[v].
// f: (16,128,256,256) fp32; out: (16,128,128,128) fp32. Memory-bound:
// ideal ~620 MB fetch + 134 MB write -> ~120 us at 6.3 TB/s.

#define KS 7
#define PAD 3
#define H 256
#define W 256
#define HO 128
#define WO 128
#define TH 32            // output tile rows per block
#define TW 32            // output tile cols per block
#define ROWS 69          // input rows needed: 2*TH+5
#define COLS 72          // input floats per row (18 float4), covers 69 + align slack
#define C4N 18           // float4s per row
#define SSTRIDE 76       // LDS input row stride; 76%32==12 -> b128 reads spread all banks
#define GSTRIDE 36       // LDS g row stride; 36%32==4 -> b128 reads spread all banks

__global__ __launch_bounds__(256)
void pp_kernel(const float* __restrict__ f, const float* __restrict__ tptr,
               float* __restrict__ out) {
    __shared__ float sin_[ROWS * SSTRIDE];   // 20976 B
    __shared__ float g_[ROWS * GSTRIDE];     //  9936 B  (30.9 KB -> 5 blocks/CU)

    const int tid   = threadIdx.x;
    const int blk   = blockIdx.x;
    const int tile  = blk & 15;        // 4x4 tiles per (b,c) plane
    const int plane = blk >> 4;        // b*128 + c
    const int i0 = (tile >> 2) * TH;
    const int j0 = (tile & 3) * TW;

    const float inv4t = -0.25f / tptr[0];
    float hu[KS];
#pragma unroll
    for (int v = 0; v < KS; ++v) {
        const float z = (float)(v - PAD);
        hu[v] = (z * z) * inv4t;
    }

    const int gy0 = 2 * i0 - 3;        // global row of LDS row 0
    const int gx0 = 2 * j0 - 4;        // global col of LDS col 0 (x4-aligned)
    const float* fplane = f + (size_t)plane * (H * W);
    const float NEG = -__builtin_inff();

    // ---- Phase 1: global -> LDS, branchless (clamped addr + select), 5 loads in flight ----
#pragma unroll
    for (int k = 0; k < 5; ++k) {
        int idx = tid + (k << 8);
        if (idx > ROWS * C4N - 1) idx = ROWS * C4N - 1;   // benign duplicate
        const int r  = idx / C4N;
        const int c4 = idx - r * C4N;
        const int gy = gy0 + r;
        const int gx = gx0 + (c4 << 2);
        const bool valid = ((unsigned)gy < (unsigned)H) & ((unsigned)gx < (unsigned)W);
        const int off = valid ? (gy * W + gx) : 0;
        float4 val = *(const float4*)(fplane + off);
        if (!valid) val = make_float4(NEG, NEG, NEG, NEG);
        *(float4*)(&sin_[r * SSTRIDE + (c4 << 2)]) = val;
    }
    __syncthreads();

    // ---- Phase 2: horizontal max-plus: g[y][jj] = max_v sin[y][2jj+1+v] + hu[v] ----
    // 552 = 69 rows x 8 col-groups work items, flat distribution
#pragma unroll
    for (int k = 0; k < 3; ++k) {
        int idx = tid + (k << 8);
        if (idx > ROWS * 8 - 1) idx = ROWS * 8 - 1;       // benign duplicate
        const int y = idx >> 3;
        const int q = idx & 7;          // g cols 4q..4q+3, window local x in [8q, 8q+16)
        const float* row = &sin_[y * SSTRIDE + (q << 3)]; // 16B-aligned
        const float4 w0 = *(const float4*)(row);
        const float4 w1 = *(const float4*)(row + 4);
        const float4 w2 = *(const float4*)(row + 8);
        const float4 w3 = *(const float4*)(row + 12);
        const float s[16] = {w0.x, w0.y, w0.z, w0.w, w1.x, w1.y, w1.z, w1.w,
                             w2.x, w2.y, w2.z, w2.w, w3.x, w3.y, w3.z, w3.w};
        float4 gv;
        float* gp = (float*)&gv;
#pragma unroll
        for (int jj = 0; jj < 4; ++jj) {
            float m = s[2 * jj + 1] + hu[0];
#pragma unroll
            for (int v = 1; v < KS; ++v)
                m = fmaxf(m, s[2 * jj + 1 + v] + hu[v]);
            gp[jj] = m;
        }
        *(float4*)(&g_[y * GSTRIDE + (q << 2)]) = gv;
    }
    __syncthreads();

    // ---- Phase 3: vertical max-plus, b128 LDS reads, float4 coalesced store ----
    {
        const int q = tid & 7;          // col group 4q..4q+3
        const int i = tid >> 3;         // output row 0..31
        float4 m;
        {
            const float4 w = *(const float4*)(&g_[(2 * i) * GSTRIDE + (q << 2)]);
            m.x = w.x + hu[0]; m.y = w.y + hu[0]; m.z = w.z + hu[0]; m.w = w.w + hu[0];
        }
#pragma unroll
        for (int u = 1; u < KS; ++u) {
            const float4 w = *(const float4*)(&g_[(2 * i + u) * GSTRIDE + (q << 2)]);
            const float hv = hu[u];
            m.x = fmaxf(m.x, w.x + hv);
            m.y = fmaxf(m.y, w.y + hv);
            m.z = fmaxf(m.z, w.z + hv);
            m.w = fmaxf(m.w, w.w + hv);
        }
        float* oplane = out + (size_t)plane * (HO * WO);
        *(float4*)(oplane + (size_t)(i0 + i) * WO + j0 + (q << 2)) = m;
    }
}

extern "C" void kernel_launch(void* const* d_in, const int* in_sizes, int n_in,
                              void* d_out, int out_size, void* d_ws, size_t ws_size,
                              hipStream_t stream) {
    const float* f = (const float*)d_in[0];
    const float* t = (const float*)d_in[1];
    float* out = (float*)d_out;
    pp_kernel<<<dim3(2048 * 16), dim3(256), 0, stream>>>(f, t, out);
}